// Round 11
// baseline (247.684 us; speedup 1.0000x reference)
//
#include <hip/hip_runtime.h>
#include <hip/hip_bf16.h>
#include <string.h>

// MultiHeadAttention: B=1, L=4096, D=1024, H=16, HD=64, causal.
// R11: attention redesigned for 2 independent blocks/CU: 256-thread blocks
// (4 waves x M=32, full row ownership -> no merge buffer), LDS 50.4KB,
// complementary grid pairing (bid & bid+256 -> same CU, tile totals sum to 66
// exactly). Barriers couple only 4 waves; co-resident blocks overlap each
// other's staging drains. prep/gemm_qkv/gemm_proj unchanged from R10.

typedef unsigned short ushort_t;
typedef __attribute__((ext_vector_type(8))) short short8;
typedef __attribute__((ext_vector_type(4))) float f32x4;

#define MFMA16(a, b, c) __builtin_amdgcn_mfma_f32_16x16x32_bf16(a, b, c, 0, 0, 0)

static constexpr int Lq = 4096;
static constexpr int Dm = 1024;
static constexpr int NH = 16;
static constexpr int HD = 64;
static constexpr int D3 = 3072;
static constexpr float SCALE_LOG2E = 0.125f * 1.44269504088896340736f;

__device__ __forceinline__ ushort_t f2bf(float f) {
    union { float f; unsigned int u; } x{f};
    unsigned int u = x.u;
    u += 0x7fffu + ((u >> 16) & 1u);   // RNE
    return (ushort_t)(u >> 16);
}

// packed fp32x2 -> bf16x2 (compiler emits v_cvt_pk_bf16_f32), RNE
__device__ __forceinline__ unsigned int cvtpk(float a, float b) {
    __hip_bfloat162 h = __float22bfloat162_rn(make_float2(a, b));
    unsigned int u;
    memcpy(&u, &h, 4);
    return u;
}

__device__ __forceinline__ void gl2lds16(const ushort_t* g, ushort_t* l) {
    __builtin_amdgcn_global_load_lds(
        (const __attribute__((address_space(1))) unsigned int*)g,
        (__attribute__((address_space(3))) unsigned int*)l, 16, 0, 0);
}

// ---------------- prep: cvt X->bf16 + transpose-convert both W ----------------
__global__ void __launch_bounds__(256)
prep(const float* __restrict__ X, const float* __restrict__ Wqkv,
     const float* __restrict__ Wproj, ushort_t* __restrict__ Xb,
     ushort_t* __restrict__ WqkvT, ushort_t* __restrict__ WprojT) {
    __shared__ float tile[32][33];
    const int bid = blockIdx.x, tid = threadIdx.x;
    if (bid < 4096) {
        int i = (bid * 256 + tid) * 4;
        float4 v = *(const float4*)&X[i];
        ushort_t r[4] = { f2bf(v.x), f2bf(v.y), f2bf(v.z), f2bf(v.w) };
        *(uint2*)&Xb[i] = *(uint2*)r;
        return;
    }
    const float* W; ushort_t* Wt; int Nd, nb, kb;
    if (bid < 7168) {
        int b = bid - 4096; W = Wqkv;  Wt = WqkvT;  Nd = 3072;
        nb = (b % 96) * 32; kb = (b / 96) * 32;
    } else {
        int b = bid - 7168; W = Wproj; Wt = WprojT; Nd = 1024;
        nb = (b % 32) * 32; kb = (b / 32) * 32;
    }
    const int tx = tid & 31, ty = tid >> 5;
    for (int j = 0; j < 32; j += 8)
        tile[ty + j][tx] = W[(size_t)(kb + ty + j) * Nd + nb + tx];
    __syncthreads();
    for (int j = 0; j < 32; j += 8)
        Wt[(size_t)(nb + ty + j) * Dm + kb + tx] = f2bf(tile[tx][ty + j]);
}

// ---------------- QKV GEMM with fused V-transpose epilogue ----------------
__global__ void __launch_bounds__(256)
gemm_qkv(const ushort_t* __restrict__ A, const ushort_t* __restrict__ Bt,
         const float* __restrict__ bias, ushort_t* __restrict__ Cq,
         ushort_t* __restrict__ Vt) {
    __shared__ alignas(16) ushort_t Alds[128 * 32];
    __shared__ alignas(16) ushort_t Blds[128 * 32];
    const int tid  = threadIdx.x;
    const int lane = tid & 63;
    const int w    = tid >> 6;
    const int quad = lane >> 4;
    const int l16  = lane & 15;
    const int mbase = blockIdx.x * 128;
    const int nbase = blockIdx.y * 128;
    const int moff  = (w >> 1) * 64;
    const int noff  = (w & 1) * 64;
    const int K = Dm;

    f32x4 acc[4][4] = {};

    for (int kb = 0; kb < K; kb += 32) {
        __syncthreads();
        #pragma unroll
        for (int c = 0; c < 2; c++) {
            int id  = w * 128 + c * 64 + lane;
            int row = id >> 2, col = (id & 3) * 8;
            gl2lds16(&A[(size_t)(mbase + row) * K + kb + col], &Alds[(size_t)(w * 128 + c * 64) * 8]);
            gl2lds16(&Bt[(size_t)(nbase + row) * K + kb + col], &Blds[(size_t)(w * 128 + c * 64) * 8]);
        }
        __syncthreads();
        short8 a[4], b[4];
        #pragma unroll
        for (int m = 0; m < 4; m++)
            a[m] = *(const short8*)&Alds[(moff + m * 16 + l16) * 32 + quad * 8];
        #pragma unroll
        for (int n = 0; n < 4; n++)
            b[n] = *(const short8*)&Blds[(noff + n * 16 + l16) * 32 + quad * 8];
        #pragma unroll
        for (int m = 0; m < 4; m++)
            #pragma unroll
            for (int n = 0; n < 4; n++)
                acc[m][n] = MFMA16(a[m], b[n], acc[m][n]);
    }

    if (nbase < 2048) {
        const bool qscale = (nbase < 1024);
        #pragma unroll
        for (int m = 0; m < 4; m++)
            #pragma unroll
            for (int n = 0; n < 4; n++)
                #pragma unroll
                for (int r = 0; r < 4; r++) {
                    int row = mbase + moff + m * 16 + quad * 4 + r;
                    int col = nbase + noff + n * 16 + l16;
                    float v = acc[m][n][r] + bias[col];
                    if (qscale) v *= SCALE_LOG2E;
                    Cq[(size_t)row * D3 + col] = f2bf(v);
                }
    } else {
        // V block: write transposed + key-permuted (4 b16 stores per 32B sector)
        #pragma unroll
        for (int m = 0; m < 4; m++)
            #pragma unroll
            for (int r = 0; r < 4; r++) {
                const int key = mbase + moff + m * 16 + quad * 4 + r;
                const int cp  = (key & ~63) + ((key & 15) * 4 + ((key >> 4) & 3));
                #pragma unroll
                for (int n = 0; n < 4; n++) {
                    const int col = nbase + noff + n * 16 + l16;
                    float v = acc[m][n][r] + bias[col];
                    Vt[(size_t)(col - 2048) * Lq + cp] = f2bf(v);
                }
            }
    }
}

// ---------------- flash attention (R11) ----------------
// grid 512 complementary-paired: bid<256 -> c = 31-(bid>>4); bid>=256 ->
// c = (bid-256)>>4. h = bid & 15 (XCD pin; paired blocks share h => shared
// K/V in L2). block 256 = 4 waves x 32 q rows, full ownership (no merge).
// K/V double-buffered LDS (50.4KB total -> 2 blocks/CU); stage for tile kt+1
// issued after the loop-top barrier; causal mask on tiles kt >= 2c.
__global__ void __launch_bounds__(256, 2)
attn_fwd(const ushort_t* __restrict__ qkv, const ushort_t* __restrict__ Vt,
         ushort_t* __restrict__ O) {
    __shared__ alignas(16) ushort_t Kl[2][64 * 64];
    __shared__ alignas(16) ushort_t Vl[2][64 * 64];
    __shared__ alignas(16) ushort_t Pl[4 * 32 * 72];

    const int tid  = threadIdx.x;
    const int lane = tid & 63;
    const int w    = tid >> 6;          // [0,4)
    const int quad = lane >> 4;
    const int l16  = lane & 15;
    const int bid  = blockIdx.x;
    const int h    = bid & 15;
    const int j    = bid >> 4;          // [0,32)
    const int c    = (bid < 256) ? (31 - j) : (j - 16);
    const int qw   = c * 128 + w * 32;  // wave's 32 query rows
    const int nt   = 2 * c + 2;
    ushort_t* pw   = Pl + w * 32 * 72;
    const float NEG_INF = -__builtin_inff();
    const int sw   = l16 & 7;

    const short bf1 = (short)0x3F80;
    const short8 ones = { bf1, bf1, bf1, bf1, bf1, bf1, bf1, bf1 };

    const ushort_t* kbase = qkv + Dm + h * HD;           // K rows, stride D3
    const ushort_t* vbase = Vt + (size_t)h * HD * Lq;    // V^T rows, stride Lq

    // Q A-fragments (exp2-domain, pre-scaled in GEMM epilogue)
    short8 qf[2][2];
    #pragma unroll
    for (int m = 0; m < 2; m++) {
        const ushort_t* qr = qkv + (size_t)(qw + m * 16 + l16) * D3 + h * HD;
        qf[m][0] = *(const short8*)(qr + quad * 8);
        qf[m][1] = *(const short8*)(qr + 32 + quad * 8);
    }

    f32x4 o[2][4] = {};
    f32x4 lacc[2] = {};

    // loop-invariant LDS fragment offsets (shared by K and V reads)
    int kvo[4][2];
    #pragma unroll
    for (int s = 0; s < 4; s++)
        #pragma unroll
        for (int kh = 0; kh < 2; kh++)
            kvo[s][kh] = (s * 16 + l16) * 64 + (((kh * 4 + quad) ^ sw) * 8);

    // staging: 512 granules of 16B per tile; thread covers granules
    // gA = w*64+lane and gB = 256+w*64+lane (wave-uniform LDS bases).
    // granule g -> tile row g>>3, swizzled source col (g&7)^(row&7).
    const int gA = w * 64 + lane;
    const int rA = gA >> 3, cA = (gA & 7) ^ (rA & 7);
    const int gB = 256 + w * 64 + lane;
    const int rB = gB >> 3, cB = (gB & 7) ^ (rB & 7);
    const ushort_t* ksA = kbase + (size_t)rA * D3 + cA * 8;
    const ushort_t* ksB = kbase + (size_t)rB * D3 + cB * 8;
    const ushort_t* vsA = vbase + (size_t)rA * Lq + cA * 8;
    const ushort_t* vsB = vbase + (size_t)rB * Lq + cB * 8;
    const int dA = w * 512, dB = 2048 + w * 512;

    auto stage = [&](int kt, int b) {
        const size_t ko = (size_t)kt * 64 * D3;
        const int    vo = kt * 64;
        gl2lds16(ksA + ko, &Kl[b][dA]);
        gl2lds16(ksB + ko, &Kl[b][dB]);
        gl2lds16(vsA + vo, &Vl[b][dA]);
        gl2lds16(vsB + vo, &Vl[b][dB]);
    };

    stage(0, 0);

    for (int kt = 0; kt < nt; kt++) {
        const int buf = kt & 1;
        __syncthreads();                 // tile kt staged & visible; buf^1 free
        if (kt + 1 < nt) stage(kt + 1, buf ^ 1);

        const ushort_t* Kb = &Kl[buf][0];
        const ushort_t* Vb = &Vl[buf][0];
        const int k0 = kt * 64;
        const bool domask = (kt >= 2 * c);

        short8 kf[4][2];
        #pragma unroll
        for (int s = 0; s < 4; s++)
            #pragma unroll
            for (int kh = 0; kh < 2; kh++)
                kf[s][kh] = *(const short8*)&Kb[kvo[s][kh]];

        f32x4 st[2][4];
        #pragma unroll
        for (int m = 0; m < 2; m++)
            #pragma unroll
            for (int s = 0; s < 4; s++) {
                f32x4 t = {};
                t = MFMA16(qf[m][0], kf[s][0], t);
                t = MFMA16(qf[m][1], kf[s][1], t);
                st[m][s] = t;
            }

        #pragma unroll
        for (int m = 0; m < 2; m++)
            #pragma unroll
            for (int r4 = 0; r4 < 4; r4++) {
                float e[4];
                #pragma unroll
                for (int s = 0; s < 4; s++) {
                    float v = st[m][s][r4];
                    if (domask) {
                        const int qg = qw + m * 16 + quad * 4 + r4;
                        if (k0 + s * 16 + l16 > qg) v = NEG_INF;
                    }
                    e[s] = __builtin_amdgcn_exp2f(v);
                }
                uint2 pk = { cvtpk(e[0], e[1]), cvtpk(e[2], e[3]) };
                *(uint2*)&pw[(m * 16 + quad * 4 + r4) * 72 + l16 * 4] = pk;
            }

        short8 pf[2][2];
        #pragma unroll
        for (int m = 0; m < 2; m++)
            #pragma unroll
            for (int kh = 0; kh < 2; kh++)
                pf[m][kh] = *(const short8*)&pw[(m * 16 + l16) * 72 + kh * 32 + quad * 8];
        #pragma unroll
        for (int m = 0; m < 2; m++) {
            lacc[m] = MFMA16(pf[m][0], ones, lacc[m]);
            lacc[m] = MFMA16(pf[m][1], ones, lacc[m]);
        }

        short8 vf[4][2];
        #pragma unroll
        for (int t = 0; t < 4; t++)
            #pragma unroll
            for (int kh = 0; kh < 2; kh++)
                vf[t][kh] = *(const short8*)&Vb[kvo[t][kh]];
        #pragma unroll
        for (int m = 0; m < 2; m++)
            #pragma unroll
            for (int t = 0; t < 4; t++) {
                o[m][t] = MFMA16(pf[m][0], vf[t][0], o[m][t]);
                o[m][t] = MFMA16(pf[m][1], vf[t][1], o[m][t]);
            }
    }

    // epilogue: full ownership, no merge
    #pragma unroll
    for (int m = 0; m < 2; m++)
        #pragma unroll
        for (int r4 = 0; r4 < 4; r4++) {
            const float inv = 1.0f / lacc[m][r4];
            ushort_t* orow = O + (size_t)(qw + m * 16 + quad * 4 + r4) * Dm + h * HD;
            #pragma unroll
            for (int t = 0; t < 4; t++)
                orow[t * 16 + l16] = f2bf(o[m][t][r4] * inv);
        }
}

// ---------------- proj GEMM: 128x64 tiles (512 blocks = 2/CU) ----------------
__global__ void __launch_bounds__(256)
gemm_proj(const ushort_t* __restrict__ A, const ushort_t* __restrict__ Bt,
          const float* __restrict__ bias, float* __restrict__ C) {
    __shared__ alignas(16) ushort_t Alds[128 * 32];
    __shared__ alignas(16) ushort_t Blds[64 * 32];
    const int tid  = threadIdx.x;
    const int lane = tid & 63;
    const int w    = tid >> 6;
    const int quad = lane >> 4;
    const int l16  = lane & 15;
    const int mbase = blockIdx.x * 128;
    const int nbase = blockIdx.y * 64;
    const int moff  = (w >> 1) * 64;
    const int noff  = (w & 1) * 32;
    const int K = Dm, N = Dm;

    f32x4 acc[4][2] = {};

    for (int kb = 0; kb < K; kb += 32) {
        __syncthreads();
        #pragma unroll
        for (int c = 0; c < 2; c++) {
            int id  = w * 128 + c * 64 + lane;
            int row = id >> 2, col = (id & 3) * 8;
            gl2lds16(&A[(size_t)(mbase + row) * K + kb + col], &Alds[(size_t)(w * 128 + c * 64) * 8]);
        }
        {
            int id  = w * 64 + lane;
            int row = id >> 2, col = (id & 3) * 8;
            gl2lds16(&Bt[(size_t)(nbase + row) * K + kb + col], &Blds[(size_t)(w * 64) * 8]);
        }
        __syncthreads();
        short8 a[4], b[2];
        #pragma unroll
        for (int m = 0; m < 4; m++)
            a[m] = *(const short8*)&Alds[(moff + m * 16 + l16) * 32 + quad * 8];
        #pragma unroll
        for (int n = 0; n < 2; n++)
            b[n] = *(const short8*)&Blds[(noff + n * 16 + l16) * 32 + quad * 8];
        #pragma unroll
        for (int m = 0; m < 4; m++)
            #pragma unroll
            for (int n = 0; n < 2; n++)
                acc[m][n] = MFMA16(a[m], b[n], acc[m][n]);
    }

    #pragma unroll
    for (int m = 0; m < 4; m++)
        #pragma unroll
        for (int n = 0; n < 2; n++)
            #pragma unroll
            for (int r = 0; r < 4; r++) {
                int row = mbase + moff + m * 16 + quad * 4 + r;
                int col = nbase + noff + n * 16 + l16;
                C[(size_t)row * N + col] = acc[m][n][r] + bias[col];
            }
}

// ---------------- launch ----------------
extern "C" void kernel_launch(void* const* d_in, const int* in_sizes, int n_in,
                              void* d_out, int out_size, void* d_ws, size_t ws_size,
                              hipStream_t stream) {
    const float* X     = (const float*)d_in[0];
    const float* Wqkv  = (const float*)d_in[1];
    const float* bqkv  = (const float*)d_in[2];
    const float* Wproj = (const float*)d_in[3];
    const float* bproj = (const float*)d_in[4];
    float* out = (float*)d_out;

    ushort_t* ws     = (ushort_t*)d_ws;
    ushort_t* Xb     = ws;                               // 4096x1024
    ushort_t* WqkvT  = Xb + (size_t)Lq * Dm;             // 3072x1024
    ushort_t* WprojT = WqkvT + (size_t)D3 * Dm;          // 1024x1024
    ushort_t* qkvB   = WprojT + (size_t)Dm * Dm;         // 4096x3072 (Q,K used)
    ushort_t* VtB    = qkvB + (size_t)Lq * D3;           // 16x64x4096
    ushort_t* Ob     = VtB + (size_t)NH * HD * Lq;       // 4096x1024

    prep<<<dim3(8192), 256, 0, stream>>>(X, Wqkv, Wproj, Xb, WqkvT, WprojT);

    gemm_qkv<<<dim3(Lq / 128, D3 / 128), 256, 0, stream>>>(
        Xb, WqkvT, bqkv, qkvB, VtB);

    attn_fwd<<<dim3(512), 256, 0, stream>>>(qkvB, VtB, Ob);

    gemm_proj<<<dim3(Lq / 128, Dm / 64), 256, 0, stream>>>(
        Ob, WprojT, bproj, out);
}

// Round 12
// 212.407 us; speedup vs baseline: 1.1661x; 1.1661x over previous
//
#include <hip/hip_runtime.h>
#include <hip/hip_bf16.h>
#include <string.h>

// MultiHeadAttention: B=1, L=4096, D=1024, H=16, HD=64, causal.
// R12: attention reverted to R9 (best known: intra-block pairing keeps 8
// waves resident the whole kernel; R11's inter-block pairing let light blocks
// retire early -> 4 waves/CU tail). gemm_qkv V-epilogue scatter fixed via
// C-layout packing: cp=(quad*4+r)*4+m => consecutive-m registers are 8
// consecutive permuted columns -> b128 stores (was 64x 2B scatter/lane).

typedef unsigned short ushort_t;
typedef __attribute__((ext_vector_type(8))) short short8;
typedef __attribute__((ext_vector_type(4))) float f32x4;

#define MFMA16(a, b, c) __builtin_amdgcn_mfma_f32_16x16x32_bf16(a, b, c, 0, 0, 0)

static constexpr int Lq = 4096;
static constexpr int Dm = 1024;
static constexpr int NH = 16;
static constexpr int HD = 64;
static constexpr int D3 = 3072;
static constexpr float SCALE_LOG2E = 0.125f * 1.44269504088896340736f;

__device__ __forceinline__ ushort_t f2bf(float f) {
    union { float f; unsigned int u; } x{f};
    unsigned int u = x.u;
    u += 0x7fffu + ((u >> 16) & 1u);   // RNE
    return (ushort_t)(u >> 16);
}

// packed fp32x2 -> bf16x2 (compiler emits v_cvt_pk_bf16_f32), RNE
__device__ __forceinline__ unsigned int cvtpk(float a, float b) {
    __hip_bfloat162 h = __float22bfloat162_rn(make_float2(a, b));
    unsigned int u;
    memcpy(&u, &h, 4);
    return u;
}

__device__ __forceinline__ void gl2lds16(const ushort_t* g, ushort_t* l) {
    __builtin_amdgcn_global_load_lds(
        (const __attribute__((address_space(1))) unsigned int*)g,
        (__attribute__((address_space(3))) unsigned int*)l, 16, 0, 0);
}

// ---------------- prep: cvt X->bf16 + transpose-convert both W ----------------
__global__ void __launch_bounds__(256)
prep(const float* __restrict__ X, const float* __restrict__ Wqkv,
     const float* __restrict__ Wproj, ushort_t* __restrict__ Xb,
     ushort_t* __restrict__ WqkvT, ushort_t* __restrict__ WprojT) {
    __shared__ float tile[32][33];
    const int bid = blockIdx.x, tid = threadIdx.x;
    if (bid < 4096) {
        int i = (bid * 256 + tid) * 4;
        float4 v = *(const float4*)&X[i];
        ushort_t r[4] = { f2bf(v.x), f2bf(v.y), f2bf(v.z), f2bf(v.w) };
        *(uint2*)&Xb[i] = *(uint2*)r;
        return;
    }
    const float* W; ushort_t* Wt; int Nd, nb, kb;
    if (bid < 7168) {
        int b = bid - 4096; W = Wqkv;  Wt = WqkvT;  Nd = 3072;
        nb = (b % 96) * 32; kb = (b / 96) * 32;
    } else {
        int b = bid - 7168; W = Wproj; Wt = WprojT; Nd = 1024;
        nb = (b % 32) * 32; kb = (b / 32) * 32;
    }
    const int tx = tid & 31, ty = tid >> 5;
    for (int j = 0; j < 32; j += 8)
        tile[ty + j][tx] = W[(size_t)(kb + ty + j) * Nd + nb + tx];
    __syncthreads();
    for (int j = 0; j < 32; j += 8)
        Wt[(size_t)(nb + ty + j) * Dm + kb + tx] = f2bf(tile[tx][ty + j]);
}

// ---------------- QKV GEMM with fused V-transpose epilogue ----------------
// cols [0,1024): *SCALE_LOG2E -> qkvB (Q); [1024,2048): -> qkvB (K);
// [2048,3072): transposed+key-permuted to Vt via packed b128 stores.
__global__ void __launch_bounds__(256)
gemm_qkv(const ushort_t* __restrict__ A, const ushort_t* __restrict__ Bt,
         const float* __restrict__ bias, ushort_t* __restrict__ Cq,
         ushort_t* __restrict__ Vt) {
    __shared__ alignas(16) ushort_t Alds[128 * 32];
    __shared__ alignas(16) ushort_t Blds[128 * 32];
    const int tid  = threadIdx.x;
    const int lane = tid & 63;
    const int w    = tid >> 6;
    const int quad = lane >> 4;
    const int l16  = lane & 15;
    const int mbase = blockIdx.x * 128;
    const int nbase = blockIdx.y * 128;
    const int moff  = (w >> 1) * 64;
    const int noff  = (w & 1) * 64;
    const int K = Dm;

    f32x4 acc[4][4] = {};

    for (int kb = 0; kb < K; kb += 32) {
        __syncthreads();
        #pragma unroll
        for (int c = 0; c < 2; c++) {
            int id  = w * 128 + c * 64 + lane;
            int row = id >> 2, col = (id & 3) * 8;
            gl2lds16(&A[(size_t)(mbase + row) * K + kb + col], &Alds[(size_t)(w * 128 + c * 64) * 8]);
            gl2lds16(&Bt[(size_t)(nbase + row) * K + kb + col], &Blds[(size_t)(w * 128 + c * 64) * 8]);
        }
        __syncthreads();
        short8 a[4], b[4];
        #pragma unroll
        for (int m = 0; m < 4; m++)
            a[m] = *(const short8*)&Alds[(moff + m * 16 + l16) * 32 + quad * 8];
        #pragma unroll
        for (int n = 0; n < 4; n++)
            b[n] = *(const short8*)&Blds[(noff + n * 16 + l16) * 32 + quad * 8];
        #pragma unroll
        for (int m = 0; m < 4; m++)
            #pragma unroll
            for (int n = 0; n < 4; n++)
                acc[m][n] = MFMA16(a[m], b[n], acc[m][n]);
    }

    if (nbase < 2048) {
        const bool qscale = (nbase < 1024);
        #pragma unroll
        for (int m = 0; m < 4; m++)
            #pragma unroll
            for (int n = 0; n < 4; n++)
                #pragma unroll
                for (int r = 0; r < 4; r++) {
                    int row = mbase + moff + m * 16 + quad * 4 + r;
                    int col = nbase + noff + n * 16 + l16;
                    float v = acc[m][n][r] + bias[col];
                    if (qscale) v *= SCALE_LOG2E;
                    Cq[(size_t)row * D3 + col] = f2bf(v);
                }
    } else {
        // V block: key64 = m*16 + quad*4 + r -> cp = (quad*4+r)*4 + m.
        // For fixed (quad, r-pair): m-registers give 8 consecutive columns.
        const int dbase = nbase - 2048 + noff;
        const size_t kb0 = (size_t)mbase + moff;   // 64-aligned key window
        #pragma unroll
        for (int n = 0; n < 4; n++) {
            const float bv = bias[nbase + noff + n * 16 + l16];
            ushort_t* vrow = Vt + (size_t)(dbase + n * 16 + l16) * Lq + kb0 + quad * 16;
            #pragma unroll
            for (int rp = 0; rp < 2; rp++) {
                ushort_t pk[8];
                #pragma unroll
                for (int dr = 0; dr < 2; dr++)
                    #pragma unroll
                    for (int m = 0; m < 4; m++)
                        pk[dr * 4 + m] = f2bf(acc[m][n][2 * rp + dr] + bv);
                *(short8*)(vrow + rp * 8) = *(const short8*)pk;
            }
        }
    }
}

// ---------------- flash attention (R9, reverted) ----------------
// grid 256 = 16 pairs x 16 heads; head = bid & 15 (XCD pin); p = bid >> 4.
// block 512 = 8 waves: half = w>>2 (even/odd 64-key tiles), sub = w&3.
// sel 0: chunk p; sel 1: chunk 31-p => 34 rounds/block, uniform, 8 waves
// resident throughout. Halves sum-merge (O,l) through LDS per sel.
__global__ void __launch_bounds__(512, 2)
attn_fwd(const ushort_t* __restrict__ qkv, const ushort_t* __restrict__ Vt,
         ushort_t* __restrict__ O) {
    __shared__ alignas(16) ushort_t Kl[2][2][64 * 64];   // [half][buf]
    __shared__ alignas(16) ushort_t Vl[2][2][64 * 64];
    __shared__ alignas(16) ushort_t Pl[8 * 32 * 72];
    __shared__ alignas(16) float    Ml[256 * 41];        // merge: pitch 41

    const int tid  = threadIdx.x;
    const int lane = tid & 63;
    const int w    = tid >> 6;          // [0,8)
    const int half = w >> 2;            // 0: even tiles, 1: odd tiles
    const int sub  = w & 3;             // q sub-chunk
    const int quad = lane >> 4;
    const int l16  = lane & 15;
    const int bid  = blockIdx.x;
    const int h    = bid & 15;
    const int p    = bid >> 4;          // [0,16)
    ushort_t* pw   = Pl + w * 32 * 72;
    const float NEG_INF = -__builtin_inff();
    const int sw   = l16 & 7;

    const short bf1 = (short)0x3F80;
    const short8 ones = { bf1, bf1, bf1, bf1, bf1, bf1, bf1, bf1 };

    const ushort_t* kbase = qkv + Dm + h * HD;           // K rows, stride D3
    const ushort_t* vbase = Vt + (size_t)h * HD * Lq;    // V^T rows, stride Lq

    int kvo[4][2];
    #pragma unroll
    for (int s = 0; s < 4; s++)
        #pragma unroll
        for (int kh = 0; kh < 2; kh++)
            kvo[s][kh] = (s * 16 + l16) * 64 + (((kh * 4 + quad) ^ sw) * 8);

    const int rr = tid >> 3, cc = (tid & 7) ^ (rr & 7);
    const ushort_t* kse = kbase + (size_t)rr * D3 + cc * 8;
    const ushort_t* vse = vbase + (size_t)rr * Lq + cc * 8;
    const int dstoff = w * 512;

    for (int sel = 0; sel < 2; sel++) {
        const int c      = sel ? (31 - p) : p;
        const int qc     = c * 128;
        const int rounds = c + 1;
        const int qw     = qc + sub * 32;

        short8 qf[2][2];
        #pragma unroll
        for (int m = 0; m < 2; m++) {
            const ushort_t* qr = qkv + (size_t)(qw + m * 16 + l16) * D3 + h * HD;
            qf[m][0] = *(const short8*)(qr + quad * 8);
            qf[m][1] = *(const short8*)(qr + 32 + quad * 8);
        }

        f32x4 o[2][4] = {};
        f32x4 lacc[2] = {};

        const ushort_t* kp = kse;
        const ushort_t* vp = vse;

        auto stage = [&](int b) {
            gl2lds16(kp,           &Kl[0][b][dstoff]);
            gl2lds16(kp + 64 * D3, &Kl[1][b][dstoff]);
            gl2lds16(vp,           &Vl[0][b][dstoff]);
            gl2lds16(vp + 64,      &Vl[1][b][dstoff]);
            kp += (size_t)128 * D3;
            vp += 128;
        };

        stage(0);

        for (int r = 0; r < rounds; r++) {
            const int buf = r & 1;
            __syncthreads();
            if (r + 1 < rounds) stage(buf ^ 1);

            const ushort_t* Kb = &Kl[half][buf][0];
            const ushort_t* Vb = &Vl[half][buf][0];
            const int k0 = (2 * r + half) * 64;
            const bool domask = (r == rounds - 1);

            short8 kf[4][2];
            #pragma unroll
            for (int s = 0; s < 4; s++)
                #pragma unroll
                for (int kh = 0; kh < 2; kh++)
                    kf[s][kh] = *(const short8*)&Kb[kvo[s][kh]];

            f32x4 st[2][4];
            #pragma unroll
            for (int m = 0; m < 2; m++)
                #pragma unroll
                for (int s = 0; s < 4; s++) {
                    f32x4 t = {};
                    t = MFMA16(qf[m][0], kf[s][0], t);
                    t = MFMA16(qf[m][1], kf[s][1], t);
                    st[m][s] = t;
                }

            #pragma unroll
            for (int m = 0; m < 2; m++)
                #pragma unroll
                for (int r4 = 0; r4 < 4; r4++) {
                    float e[4];
                    #pragma unroll
                    for (int s = 0; s < 4; s++) {
                        float v = st[m][s][r4];
                        if (domask) {
                            const int qg = qw + m * 16 + quad * 4 + r4;
                            if (k0 + s * 16 + l16 > qg) v = NEG_INF;
                        }
                        e[s] = __builtin_amdgcn_exp2f(v);
                    }
                    uint2 pk = { cvtpk(e[0], e[1]), cvtpk(e[2], e[3]) };
                    *(uint2*)&pw[(m * 16 + quad * 4 + r4) * 72 + l16 * 4] = pk;
                }

            short8 pf[2][2];
            #pragma unroll
            for (int m = 0; m < 2; m++)
                #pragma unroll
                for (int kh = 0; kh < 2; kh++)
                    pf[m][kh] = *(const short8*)&pw[(m * 16 + l16) * 72 + kh * 32 + quad * 8];
            #pragma unroll
            for (int m = 0; m < 2; m++) {
                lacc[m] = MFMA16(pf[m][0], ones, lacc[m]);
                lacc[m] = MFMA16(pf[m][1], ones, lacc[m]);
            }

            short8 vf[4][2];
            #pragma unroll
            for (int t = 0; t < 4; t++)
                #pragma unroll
                for (int kh = 0; kh < 2; kh++)
                    vf[t][kh] = *(const short8*)&Vb[kvo[t][kh]];
            #pragma unroll
            for (int m = 0; m < 2; m++)
                #pragma unroll
                for (int t = 0; t < 4; t++) {
                    o[m][t] = MFMA16(pf[m][0], vf[t][0], o[m][t]);
                    o[m][t] = MFMA16(pf[m][1], vf[t][1], o[m][t]);
                }
        }

        __syncthreads();
        if (half == 1) {
            float* dst = Ml + (sub * 64 + lane) * 41;
            #pragma unroll
            for (int m = 0; m < 2; m++)
                #pragma unroll
                for (int t = 0; t < 4; t++)
                    *(f32x4*)(dst + m * 16 + t * 4) = o[m][t];
            *(f32x4*)(dst + 32) = lacc[0];
            *(f32x4*)(dst + 36) = lacc[1];
        }
        __syncthreads();
        if (half == 0) {
            const float* src = Ml + (sub * 64 + lane) * 41;
            #pragma unroll
            for (int m = 0; m < 2; m++)
                #pragma unroll
                for (int t = 0; t < 4; t++)
                    o[m][t] += *(const f32x4*)(src + m * 16 + t * 4);
            lacc[0] += *(const f32x4*)(src + 32);
            lacc[1] += *(const f32x4*)(src + 36);
            #pragma unroll
            for (int m = 0; m < 2; m++)
                #pragma unroll
                for (int r4 = 0; r4 < 4; r4++) {
                    const float inv = 1.0f / lacc[m][r4];
                    ushort_t* orow = O + (size_t)(qw + m * 16 + quad * 4 + r4) * Dm + h * HD;
                    #pragma unroll
                    for (int t = 0; t < 4; t++)
                        orow[t * 16 + l16] = f2bf(o[m][t][r4] * inv);
                }
        }
        __syncthreads();
    }
}

// ---------------- proj GEMM: 128x64 tiles (512 blocks = 2/CU) ----------------
__global__ void __launch_bounds__(256)
gemm_proj(const ushort_t* __restrict__ A, const ushort_t* __restrict__ Bt,
          const float* __restrict__ bias, float* __restrict__ C) {
    __shared__ alignas(16) ushort_t Alds[128 * 32];
    __shared__ alignas(16) ushort_t Blds[64 * 32];
    const int tid  = threadIdx.x;
    const int lane = tid & 63;
    const int w    = tid >> 6;
    const int quad = lane >> 4;
    const int l16  = lane & 15;
    const int mbase = blockIdx.x * 128;
    const int nbase = blockIdx.y * 64;
    const int moff  = (w >> 1) * 64;
    const int noff  = (w & 1) * 32;
    const int K = Dm, N = Dm;

    f32x4 acc[4][2] = {};

    for (int kb = 0; kb < K; kb += 32) {
        __syncthreads();
        #pragma unroll
        for (int c = 0; c < 2; c++) {
            int id  = w * 128 + c * 64 + lane;
            int row = id >> 2, col = (id & 3) * 8;
            gl2lds16(&A[(size_t)(mbase + row) * K + kb + col], &Alds[(size_t)(w * 128 + c * 64) * 8]);
        }
        {
            int id  = w * 64 + lane;
            int row = id >> 2, col = (id & 3) * 8;
            gl2lds16(&Bt[(size_t)(nbase + row) * K + kb + col], &Blds[(size_t)(w * 64) * 8]);
        }
        __syncthreads();
        short8 a[4], b[2];
        #pragma unroll
        for (int m = 0; m < 4; m++)
            a[m] = *(const short8*)&Alds[(moff + m * 16 + l16) * 32 + quad * 8];
        #pragma unroll
        for (int n = 0; n < 2; n++)
            b[n] = *(const short8*)&Blds[(noff + n * 16 + l16) * 32 + quad * 8];
        #pragma unroll
        for (int m = 0; m < 4; m++)
            #pragma unroll
            for (int n = 0; n < 2; n++)
                acc[m][n] = MFMA16(a[m], b[n], acc[m][n]);
    }

    #pragma unroll
    for (int m = 0; m < 4; m++)
        #pragma unroll
        for (int n = 0; n < 2; n++)
            #pragma unroll
            for (int r = 0; r < 4; r++) {
                int row = mbase + moff + m * 16 + quad * 4 + r;
                int col = nbase + noff + n * 16 + l16;
                C[(size_t)row * N + col] = acc[m][n][r] + bias[col];
            }
}

// ---------------- launch ----------------
extern "C" void kernel_launch(void* const* d_in, const int* in_sizes, int n_in,
                              void* d_out, int out_size, void* d_ws, size_t ws_size,
                              hipStream_t stream) {
    const float* X     = (const float*)d_in[0];
    const float* Wqkv  = (const float*)d_in[1];
    const float* bqkv  = (const float*)d_in[2];
    const float* Wproj = (const float*)d_in[3];
    const float* bproj = (const float*)d_in[4];
    float* out = (float*)d_out;

    ushort_t* ws     = (ushort_t*)d_ws;
    ushort_t* Xb     = ws;                               // 4096x1024
    ushort_t* WqkvT  = Xb + (size_t)Lq * Dm;             // 3072x1024
    ushort_t* WprojT = WqkvT + (size_t)D3 * Dm;          // 1024x1024
    ushort_t* qkvB   = WprojT + (size_t)Dm * Dm;         // 4096x3072 (Q,K used)
    ushort_t* VtB    = qkvB + (size_t)Lq * D3;           // 16x64x4096
    ushort_t* Ob     = VtB + (size_t)NH * HD * Lq;       // 4096x1024

    prep<<<dim3(8192), 256, 0, stream>>>(X, Wqkv, Wproj, Xb, WqkvT, WprojT);

    gemm_qkv<<<dim3(Lq / 128, D3 / 128), 256, 0, stream>>>(
        Xb, WqkvT, bqkv, qkvB, VtB);

    attn_fwd<<<dim3(256), 512, 0, stream>>>(qkvB, VtB, Ob);

    gemm_proj<<<dim3(Lq / 128, Dm / 64), 256, 0, stream>>>(
        Ob, WprojT, bproj, out);
}